// Round 1
// 222.370 us; speedup vs baseline: 1.1683x; 1.1683x over previous
//
// GRUCell2 MI355X — r9: single fused kernel (gather + GRU).
// r8 pipeline was seg(94us) + gru + inter-kernel drain = 259.8us total.
// Fusion: a gather block computes complete x rows for 8 channels x 8 batches
// = exactly the 64 rows one GRU block consumes. x passes through LDS as bf16
// (same conversion K2 applied from global, so numerics unchanged). Deletes:
// 32MB x write, 32MB x read, second launch + drain.
// Gather restructured: wave-per-channel, lane=(b,fquad) -> ONE dwordx4 instr
// per edge (was 3 per 2x4 edges with half-wave divergence); bounds
// readfirstlane'd so edge-index loads are scalar and the loop is uniform.
// Weights converted to bf16 once per block into LDS (was per-wave registers).
#include <hip/hip_runtime.h>

#define NB 8
#define NP 65536
#define NC 32768
#define NF 32
#define NE 524288
#define XROW 40   // shorts per LDS row (80B): 16B-aligned b128 reads, 2-way banks max

typedef __attribute__((ext_vector_type(4))) float floatx4;
typedef __attribute__((ext_vector_type(8))) short short8;
typedef __attribute__((ext_vector_type(4))) short short4v;

__device__ __forceinline__ short f2b(float f) {
    union { float f; unsigned int u; } v;
    v.f = f;
    unsigned int lsb = (v.u >> 16) & 1u;
    v.u += 0x7fffu + lsb;   // round-to-nearest-even
    return (short)(v.u >> 16);
}

__device__ __forceinline__ int lower_bound(const int* __restrict__ a, int v) {
    int lo = 0, hi = NE;
    while (lo < hi) {
        int mid = (lo + hi) >> 1;
        if (a[mid] < v) lo = mid + 1; else hi = mid;
    }
    return lo;
}

__device__ __forceinline__ float sigmoidf_(float v) {
    return 1.f / (1.f + __expf(-v));
}
__device__ __forceinline__ float tanhf_(float v) {
    v = fminf(v, 40.f);
    float t = __expf(2.f * v);
    return (t - 1.f) / (t + 1.f);
}

__global__ __launch_bounds__(256) void fused_gru_kernel(
    const float* __restrict__ path,         // [B,P,F] fp32
    const float* __restrict__ hbuf,         // [B,C,F] fp32
    const float* __restrict__ W_ih,         // [96,32] fp32
    const float* __restrict__ W_hh,         // [96,32] fp32
    const float* __restrict__ b_ih,         // [96]
    const float* __restrict__ b_hh,         // [96]
    const int*   __restrict__ edge_path,    // [E]
    const int*   __restrict__ edge_channel, // [E] sorted
    float*       __restrict__ out)          // [B,C,F] fp32
{
    const int t    = threadIdx.x;
    const int w    = t >> 6;      // wave 0..3
    const int lane = t & 63;
    const int cblk = blockIdx.x * 8;

    __shared__ int bounds[9];
    __shared__ __align__(16) short xs [64 * XROW];   // x rows, bf16, r = b*8+cl
    __shared__ __align__(16) short wsx[96 * XROW];   // W_ih bf16
    __shared__ __align__(16) short wsh[96 * XROW];   // W_hh bf16

    if (t < 9) bounds[t] = lower_bound(edge_channel, cblk + t);

    // Stage weights -> LDS bf16 once per block (24KB global, L2-hot).
    for (int idx = t; idx < 96 * NF; idx += 256) {
        int r = idx >> 5, c = idx & 31;
        wsx[r * XROW + c] = f2b(W_ih[idx]);
        wsh[r * XROW + c] = f2b(W_hh[idx]);
    }
    __syncthreads();   // bounds (and weights) visible

    // ---- Phase 1: ragged segment-sum gather. Wave w owns channels 2w, 2w+1.
    // lane = b*8 + fquad: one dwordx4 per lane covers the whole B x F row set
    // of an edge in a single wave-instruction (8 x 128B segments).
    const int b  = lane >> 3;
    const int fq = lane & 7;
    const float* prow = path + (size_t)b * (NP * NF) + fq * 4;

    #pragma unroll
    for (int half = 0; half < 2; ++half) {
        const int cl = w * 2 + half;
        const int s = __builtin_amdgcn_readfirstlane(bounds[cl]);
        const int e = __builtin_amdgcn_readfirstlane(bounds[cl + 1]);
        floatx4 acc = {0.f, 0.f, 0.f, 0.f};
        int i = s;
        for (; i + 8 <= e; i += 8) {            // 8 x 1KB gathers in flight
            int p0 = edge_path[i + 0], p1 = edge_path[i + 1];
            int p2 = edge_path[i + 2], p3 = edge_path[i + 3];
            int p4 = edge_path[i + 4], p5 = edge_path[i + 5];
            int p6 = edge_path[i + 6], p7 = edge_path[i + 7];
            floatx4 g0 = *(const floatx4*)(prow + (size_t)p0 * NF);
            floatx4 g1 = *(const floatx4*)(prow + (size_t)p1 * NF);
            floatx4 g2 = *(const floatx4*)(prow + (size_t)p2 * NF);
            floatx4 g3 = *(const floatx4*)(prow + (size_t)p3 * NF);
            floatx4 g4 = *(const floatx4*)(prow + (size_t)p4 * NF);
            floatx4 g5 = *(const floatx4*)(prow + (size_t)p5 * NF);
            floatx4 g6 = *(const floatx4*)(prow + (size_t)p6 * NF);
            floatx4 g7 = *(const floatx4*)(prow + (size_t)p7 * NF);
            acc += ((g0 + g1) + (g2 + g3)) + ((g4 + g5) + (g6 + g7));
        }
        for (; i + 2 <= e; i += 2) {
            int p0 = edge_path[i], p1 = edge_path[i + 1];
            acc += *(const floatx4*)(prow + (size_t)p0 * NF)
                 + *(const floatx4*)(prow + (size_t)p1 * NF);
        }
        if (i < e)
            acc += *(const floatx4*)(prow + (size_t)edge_path[i] * NF);

        short4v xb;
        #pragma unroll
        for (int q = 0; q < 4; ++q) xb[q] = f2b(acc[q]);
        *(short4v*)(&xs[(b * 8 + cl) * XROW + fq * 4]) = xb;
    }
    __syncthreads();

    // ---- Phase 2: fused GRU via mfma_f32_16x16x32_bf16. Wave w owns LDS
    // rows [16w, 16w+16) = 2 batches x 8 channels.
    const int quad = lane >> 4;
    const int n16  = lane & 15;
    const int k0   = quad * 8;

    const int rA = w * 16 + n16;
    short8 ax = *(const short8*)(&xs[rA * XROW + k0]);

    const int bA = rA >> 3;
    const int cA = cblk + (rA & 7);
    const float* hrow = hbuf + ((size_t)bA * NC + cA) * NF + k0;
    floatx4 h0 = *(const floatx4*)(hrow);
    floatx4 h1 = *(const floatx4*)(hrow + 4);
    short8 ah;
    #pragma unroll
    for (int q = 0; q < 4; ++q) { ah[q] = f2b(h0[q]); ah[4 + q] = f2b(h1[q]); }

    float bxv[6], bhv[6];
    #pragma unroll
    for (int tt = 0; tt < 6; ++tt) {
        bxv[tt] = b_ih[16 * tt + n16];
        bhv[tt] = b_hh[16 * tt + n16];
    }

    const floatx4 zero = {0.f, 0.f, 0.f, 0.f};
    // r,z gates: x- and h-MFMAs chain into ONE accumulator (epilogue only
    // needs the sum). n gate needs xn and hn separate (r gating on hn).
    floatx4 g[4];
    #pragma unroll
    for (int tt = 0; tt < 4; ++tt) {
        short8 bw = *(const short8*)(&wsx[(16 * tt + n16) * XROW + k0]);
        floatx4 a = __builtin_amdgcn_mfma_f32_16x16x32_bf16(ax, bw, zero, 0, 0, 0);
        bw = *(const short8*)(&wsh[(16 * tt + n16) * XROW + k0]);
        g[tt] = __builtin_amdgcn_mfma_f32_16x16x32_bf16(ah, bw, a, 0, 0, 0);
    }
    floatx4 nx[2], nh[2];
    #pragma unroll
    for (int u = 0; u < 2; ++u) {
        const int tt = 4 + u;
        short8 bw = *(const short8*)(&wsx[(16 * tt + n16) * XROW + k0]);
        nx[u] = __builtin_amdgcn_mfma_f32_16x16x32_bf16(ax, bw, zero, 0, 0, 0);
        bw = *(const short8*)(&wsh[(16 * tt + n16) * XROW + k0]);
        nh[u] = __builtin_amdgcn_mfma_f32_16x16x32_bf16(ah, bw, zero, 0, 0, 0);
    }

    // Epilogue in C-layout (col = lane&15, row = quad*4+i), fp32 h blend.
    #pragma unroll
    for (int i = 0; i < 4; ++i) {
        const int r  = w * 16 + quad * 4 + i;
        const int b2 = r >> 3;
        const size_t m = (size_t)b2 * NC + (cblk + (r & 7));
        float r0 = sigmoidf_(g[0][i] + bxv[0] + bhv[0]);
        float r1 = sigmoidf_(g[1][i] + bxv[1] + bhv[1]);
        float z0 = sigmoidf_(g[2][i] + bxv[2] + bhv[2]);
        float z1 = sigmoidf_(g[3][i] + bxv[3] + bhv[3]);
        float n0 = tanhf_(nx[0][i] + bxv[4] + r0 * (nh[0][i] + bhv[4]));
        float n1 = tanhf_(nx[1][i] + bxv[5] + r1 * (nh[1][i] + bhv[5]));
        float hv0 = hbuf[m * NF + n16];
        float hv1 = hbuf[m * NF + 16 + n16];
        out[m * NF + n16]      = (1.f - z0) * n0 + z0 * hv0;
        out[m * NF + 16 + n16] = (1.f - z1) * n1 + z1 * hv1;
    }
}

extern "C" void kernel_launch(void* const* d_in, const int* in_sizes, int n_in,
                              void* d_out, int out_size, void* d_ws, size_t ws_size,
                              hipStream_t stream) {
    const float* path = (const float*)d_in[0];  // [8,65536,32] fp32
    const float* chan = (const float*)d_in[1];  // [8,32768,32] fp32
    const float* W_ih = (const float*)d_in[2];  // [96,32]
    const float* W_hh = (const float*)d_in[3];  // [96,32]
    const float* b_ih = (const float*)d_in[4];  // [96]
    const float* b_hh = (const float*)d_in[5];  // [96]
    const int* edge_path    = (const int*)d_in[6];
    const int* edge_channel = (const int*)d_in[7];
    float* out = (float*)d_out;                 // [8,32768,32] fp32

    fused_gru_kernel<<<dim3(NC / 8), dim3(256), 0, stream>>>(
        path, chan, W_ih, W_hh, b_ih, b_hh, edge_path, edge_channel, out);
}

// Round 2
// 222.302 us; speedup vs baseline: 1.1686x; 1.0003x over previous
//
// GRUCell2 MI355X — r10: fp16-transposed gather (halve L2-fill lines) + fused GRU.
// r9 (120us fused): gather demand 512MB in 128B lines, 253MB L2-fill at 2.6TB/s
// dominates. Narrow dtype alone doesn't help (64B of a 128B line wasted);
// narrow + TRANSPOSE does: pathT[p][b][f] fp16 makes one edge's gather 512B
// contiguous = 4 fully-used 128B lines (was 8). fp16 (not bf16): 2^-11 rel
// rounding is far below the bf16(x) rounding already in the pipeline, so
// absmax stays at the passing 0.03125 level.
// Prepass: path[b][p][f] fp32 -> d_ws pathT[p][b][f] fp16 (32MB, ~15-20us).
// Fallback to the verified r9 fp32-gather if ws_size is too small.
#include <hip/hip_runtime.h>
#include <hip/hip_fp16.h>

#define NB 8
#define NP 65536
#define NC 32768
#define NF 32
#define NE 524288
#define XROW 40   // shorts per LDS row (80B): 16B-aligned b128 reads, 2-way banks max

typedef __attribute__((ext_vector_type(4))) float floatx4;
typedef __attribute__((ext_vector_type(8))) short short8;
typedef __attribute__((ext_vector_type(4))) short short4v;

struct h4 { __half2 lo, hi; };   // 8B: one global_load_dwordx2

__device__ __forceinline__ floatx4 h4tof4(h4 v) {
    float2 a = __half22float2(v.lo);
    float2 b = __half22float2(v.hi);
    floatx4 r; r[0] = a.x; r[1] = a.y; r[2] = b.x; r[3] = b.y;
    return r;
}

__device__ __forceinline__ short f2b(float f) {
    union { float f; unsigned int u; } v;
    v.f = f;
    unsigned int lsb = (v.u >> 16) & 1u;
    v.u += 0x7fffu + lsb;   // round-to-nearest-even
    return (short)(v.u >> 16);
}

__device__ __forceinline__ int lower_bound(const int* __restrict__ a, int v) {
    int lo = 0, hi = NE;
    while (lo < hi) {
        int mid = (lo + hi) >> 1;
        if (a[mid] < v) lo = mid + 1; else hi = mid;
    }
    return lo;
}

__device__ __forceinline__ float sigmoidf_(float v) {
    return 1.f / (1.f + __expf(-v));
}
__device__ __forceinline__ float tanhf_(float v) {
    v = fminf(v, 40.f);
    float t = __expf(2.f * v);
    return (t - 1.f) / (t + 1.f);
}

// ---------------------------------------------------------------------------
// Prepass: pathT[p][b*32+f] = fp16(path[b][p][f]). 4 floats/thread.
// Reads: 8-lane groups cover one 128B row chunk; writes: wave = 512B contig.
// ---------------------------------------------------------------------------
__global__ __launch_bounds__(256) void transpose_kernel(
    const float* __restrict__ path, __half* __restrict__ pathT)
{
    const int id = blockIdx.x * 256 + threadIdx.x;
    const int f4 = (id & 7) * 4;
    const int b  = (id >> 3) & 7;
    const int p  = id >> 6;
    floatx4 v = *(const floatx4*)(path + ((size_t)b * NP + p) * NF + f4);
    h4 o;
    o.lo = __floats2half2_rn(v[0], v[1]);
    o.hi = __floats2half2_rn(v[2], v[3]);
    *(h4*)(pathT + (size_t)p * (NB * NF) + b * NF + f4) = o;
}

// ---------------------------------------------------------------------------
// Fused gather + GRU. USET=1: gather fp16 from pathT (512B/edge contiguous).
// USET=0: r9 fp32 gather from path (fallback when ws too small).
// ---------------------------------------------------------------------------
template <int USET>
__global__ __launch_bounds__(256) void fused_gru_kernel(
    const float*  __restrict__ path,         // [B,P,F] fp32
    const __half* __restrict__ pathT,        // [P,B,F] fp16 (d_ws)
    const float*  __restrict__ hbuf,         // [B,C,F] fp32
    const float*  __restrict__ W_ih,         // [96,32] fp32
    const float*  __restrict__ W_hh,         // [96,32] fp32
    const float*  __restrict__ b_ih,         // [96]
    const float*  __restrict__ b_hh,         // [96]
    const int*    __restrict__ edge_path,    // [E]
    const int*    __restrict__ edge_channel, // [E] sorted
    float*        __restrict__ out)          // [B,C,F] fp32
{
    const int t    = threadIdx.x;
    const int w    = t >> 6;      // wave 0..3
    const int lane = t & 63;
    const int cblk = blockIdx.x * 8;

    __shared__ int bounds[9];
    __shared__ __align__(16) short xs [64 * XROW];   // x rows, bf16, r = b*8+cl
    __shared__ __align__(16) short wsx[96 * XROW];   // W_ih bf16
    __shared__ __align__(16) short wsh[96 * XROW];   // W_hh bf16

    if (t < 9) bounds[t] = lower_bound(edge_channel, cblk + t);

    // Stage weights -> LDS bf16 once per block (24KB global, L2-hot).
    for (int idx = t; idx < 96 * NF; idx += 256) {
        int r = idx >> 5, c = idx & 31;
        wsx[r * XROW + c] = f2b(W_ih[idx]);
        wsh[r * XROW + c] = f2b(W_hh[idx]);
    }
    __syncthreads();   // bounds (and weights) visible

    // ---- Phase 1: ragged segment-sum gather. Wave w owns channels 2w, 2w+1.
    // lane = b*8 + fquad. USET: one dwordx2/lane -> 512B contiguous per edge.
    const int b  = lane >> 3;
    const int fq = lane & 7;
    const float*  prow  = path  + (size_t)b * (NP * NF) + fq * 4;
    const __half* prowT = pathT + b * NF + fq * 4;

    #pragma unroll
    for (int half = 0; half < 2; ++half) {
        const int cl = w * 2 + half;
        const int s = __builtin_amdgcn_readfirstlane(bounds[cl]);
        const int e = __builtin_amdgcn_readfirstlane(bounds[cl + 1]);
        floatx4 acc = {0.f, 0.f, 0.f, 0.f};
        int i = s;
        if (USET) {
            for (; i + 8 <= e; i += 8) {
                int p0 = edge_path[i + 0], p1 = edge_path[i + 1];
                int p2 = edge_path[i + 2], p3 = edge_path[i + 3];
                int p4 = edge_path[i + 4], p5 = edge_path[i + 5];
                int p6 = edge_path[i + 6], p7 = edge_path[i + 7];
                h4 g0 = *(const h4*)(prowT + (size_t)p0 * (NB * NF));
                h4 g1 = *(const h4*)(prowT + (size_t)p1 * (NB * NF));
                h4 g2 = *(const h4*)(prowT + (size_t)p2 * (NB * NF));
                h4 g3 = *(const h4*)(prowT + (size_t)p3 * (NB * NF));
                h4 g4 = *(const h4*)(prowT + (size_t)p4 * (NB * NF));
                h4 g5 = *(const h4*)(prowT + (size_t)p5 * (NB * NF));
                h4 g6 = *(const h4*)(prowT + (size_t)p6 * (NB * NF));
                h4 g7 = *(const h4*)(prowT + (size_t)p7 * (NB * NF));
                acc += ((h4tof4(g0) + h4tof4(g1)) + (h4tof4(g2) + h4tof4(g3)))
                     + ((h4tof4(g4) + h4tof4(g5)) + (h4tof4(g6) + h4tof4(g7)));
            }
            for (; i + 2 <= e; i += 2) {
                int p0 = edge_path[i], p1 = edge_path[i + 1];
                h4 g0 = *(const h4*)(prowT + (size_t)p0 * (NB * NF));
                h4 g1 = *(const h4*)(prowT + (size_t)p1 * (NB * NF));
                acc += h4tof4(g0) + h4tof4(g1);
            }
            if (i < e)
                acc += h4tof4(*(const h4*)(prowT + (size_t)edge_path[i] * (NB * NF)));
        } else {
            for (; i + 8 <= e; i += 8) {
                int p0 = edge_path[i + 0], p1 = edge_path[i + 1];
                int p2 = edge_path[i + 2], p3 = edge_path[i + 3];
                int p4 = edge_path[i + 4], p5 = edge_path[i + 5];
                int p6 = edge_path[i + 6], p7 = edge_path[i + 7];
                floatx4 g0 = *(const floatx4*)(prow + (size_t)p0 * NF);
                floatx4 g1 = *(const floatx4*)(prow + (size_t)p1 * NF);
                floatx4 g2 = *(const floatx4*)(prow + (size_t)p2 * NF);
                floatx4 g3 = *(const floatx4*)(prow + (size_t)p3 * NF);
                floatx4 g4 = *(const floatx4*)(prow + (size_t)p4 * NF);
                floatx4 g5 = *(const floatx4*)(prow + (size_t)p5 * NF);
                floatx4 g6 = *(const floatx4*)(prow + (size_t)p6 * NF);
                floatx4 g7 = *(const floatx4*)(prow + (size_t)p7 * NF);
                acc += ((g0 + g1) + (g2 + g3)) + ((g4 + g5) + (g6 + g7));
            }
            for (; i + 2 <= e; i += 2) {
                int p0 = edge_path[i], p1 = edge_path[i + 1];
                acc += *(const floatx4*)(prow + (size_t)p0 * NF)
                     + *(const floatx4*)(prow + (size_t)p1 * NF);
            }
            if (i < e)
                acc += *(const floatx4*)(prow + (size_t)edge_path[i] * NF);
        }

        short4v xb;
        #pragma unroll
        for (int q = 0; q < 4; ++q) xb[q] = f2b(acc[q]);
        *(short4v*)(&xs[(b * 8 + cl) * XROW + fq * 4]) = xb;
    }
    __syncthreads();

    // ---- Phase 2: fused GRU via mfma_f32_16x16x32_bf16. Wave w owns LDS
    // rows [16w, 16w+16) = 2 batches x 8 channels.
    const int quad = lane >> 4;
    const int n16  = lane & 15;
    const int k0   = quad * 8;

    const int rA = w * 16 + n16;
    short8 ax = *(const short8*)(&xs[rA * XROW + k0]);

    const int bA = rA >> 3;
    const int cA = cblk + (rA & 7);
    const float* hrow = hbuf + ((size_t)bA * NC + cA) * NF + k0;
    floatx4 h0 = *(const floatx4*)(hrow);
    floatx4 h1 = *(const floatx4*)(hrow + 4);
    short8 ah;
    #pragma unroll
    for (int q = 0; q < 4; ++q) { ah[q] = f2b(h0[q]); ah[4 + q] = f2b(h1[q]); }

    float bxv[6], bhv[6];
    #pragma unroll
    for (int tt = 0; tt < 6; ++tt) {
        bxv[tt] = b_ih[16 * tt + n16];
        bhv[tt] = b_hh[16 * tt + n16];
    }

    const floatx4 zero = {0.f, 0.f, 0.f, 0.f};
    // r,z gates: x- and h-MFMAs chain into ONE accumulator. n gate needs
    // xn and hn separate (r gates hn).
    floatx4 g[4];
    #pragma unroll
    for (int tt = 0; tt < 4; ++tt) {
        short8 bw = *(const short8*)(&wsx[(16 * tt + n16) * XROW + k0]);
        floatx4 a = __builtin_amdgcn_mfma_f32_16x16x32_bf16(ax, bw, zero, 0, 0, 0);
        bw = *(const short8*)(&wsh[(16 * tt + n16) * XROW + k0]);
        g[tt] = __builtin_amdgcn_mfma_f32_16x16x32_bf16(ah, bw, a, 0, 0, 0);
    }
    floatx4 nx[2], nh[2];
    #pragma unroll
    for (int u = 0; u < 2; ++u) {
        const int tt = 4 + u;
        short8 bw = *(const short8*)(&wsx[(16 * tt + n16) * XROW + k0]);
        nx[u] = __builtin_amdgcn_mfma_f32_16x16x32_bf16(ax, bw, zero, 0, 0, 0);
        bw = *(const short8*)(&wsh[(16 * tt + n16) * XROW + k0]);
        nh[u] = __builtin_amdgcn_mfma_f32_16x16x32_bf16(ah, bw, zero, 0, 0, 0);
    }

    // Epilogue in C-layout (col = lane&15, row = quad*4+i), fp32 h blend.
    #pragma unroll
    for (int i = 0; i < 4; ++i) {
        const int r  = w * 16 + quad * 4 + i;
        const int b2 = r >> 3;
        const size_t m = (size_t)b2 * NC + (cblk + (r & 7));
        float r0 = sigmoidf_(g[0][i] + bxv[0] + bhv[0]);
        float r1 = sigmoidf_(g[1][i] + bxv[1] + bhv[1]);
        float z0 = sigmoidf_(g[2][i] + bxv[2] + bhv[2]);
        float z1 = sigmoidf_(g[3][i] + bxv[3] + bhv[3]);
        float n0 = tanhf_(nx[0][i] + bxv[4] + r0 * (nh[0][i] + bhv[4]));
        float n1 = tanhf_(nx[1][i] + bxv[5] + r1 * (nh[1][i] + bhv[5]));
        float hv0 = hbuf[m * NF + n16];
        float hv1 = hbuf[m * NF + 16 + n16];
        out[m * NF + n16]      = (1.f - z0) * n0 + z0 * hv0;
        out[m * NF + 16 + n16] = (1.f - z1) * n1 + z1 * hv1;
    }
}

extern "C" void kernel_launch(void* const* d_in, const int* in_sizes, int n_in,
                              void* d_out, int out_size, void* d_ws, size_t ws_size,
                              hipStream_t stream) {
    const float* path = (const float*)d_in[0];  // [8,65536,32] fp32
    const float* chan = (const float*)d_in[1];  // [8,32768,32] fp32
    const float* W_ih = (const float*)d_in[2];  // [96,32]
    const float* W_hh = (const float*)d_in[3];  // [96,32]
    const float* b_ih = (const float*)d_in[4];  // [96]
    const float* b_hh = (const float*)d_in[5];  // [96]
    const int* edge_path    = (const int*)d_in[6];
    const int* edge_channel = (const int*)d_in[7];
    float* out = (float*)d_out;                 // [8,32768,32] fp32

    const size_t needT = (size_t)NP * NB * NF * sizeof(__half);  // 32MB
    if (ws_size >= needT) {
        __half* pathT = (__half*)d_ws;
        transpose_kernel<<<dim3((NP * NB * NF / 4) / 256), dim3(256), 0, stream>>>(
            path, pathT);
        fused_gru_kernel<1><<<dim3(NC / 8), dim3(256), 0, stream>>>(
            path, pathT, chan, W_ih, W_hh, b_ih, b_hh, edge_path, edge_channel, out);
    } else {
        fused_gru_kernel<0><<<dim3(NC / 8), dim3(256), 0, stream>>>(
            path, (const __half*)nullptr, chan, W_ih, W_hh, b_ih, b_hh,
            edge_path, edge_channel, out);
    }
}

// Round 3
// 218.974 us; speedup vs baseline: 1.1864x; 1.0152x over previous
//
// GRUCell2 MI355X — r11: restore gather MLP (unroll-16, flat 2-channel range)
// + packed-fp16 pair pre-add.
// r10 regression analysis: dwordx2 loads halved in-flight bytes/wave (8KB->4KB)
// and mean-16-edge segments kept draining the unroll-8 pipe -> gather BW fell
// 2.6->2.0 TB/s. Fix: 16 loads in flight, and the wave's TWO channels form one
// contiguous sorted edge range -> stream chunks of 16 across the boundary
// (wave-uniform channel select per chunk; per-edge only for the one straddling
// chunk + tail). Pair pre-add in v_pk_add_f16 halves gather VALU (error 2^-11,
// far below fp16 storage rounding already present).
#include <hip/hip_runtime.h>
#include <hip/hip_fp16.h>

#define NB 8
#define NP 65536
#define NC 32768
#define NF 32
#define NE 524288
#define XROW 40   // shorts per LDS row (80B): 16B-aligned b128 reads, 2-way banks max

typedef __attribute__((ext_vector_type(4))) float floatx4;
typedef __attribute__((ext_vector_type(8))) short short8;
typedef __attribute__((ext_vector_type(4))) short short4v;

struct h4 { __half2 lo, hi; };   // 8B: one global_load_dwordx2
struct h8 { __half2 a, b, c, d; };  // 16B

__device__ __forceinline__ floatx4 h4tof4(h4 v) {
    float2 a = __half22float2(v.lo);
    float2 b = __half22float2(v.hi);
    floatx4 r; r[0] = a.x; r[1] = a.y; r[2] = b.x; r[3] = b.y;
    return r;
}

__device__ __forceinline__ short f2b(float f) {
    union { float f; unsigned int u; } v;
    v.f = f;
    unsigned int lsb = (v.u >> 16) & 1u;
    v.u += 0x7fffu + lsb;   // round-to-nearest-even
    return (short)(v.u >> 16);
}

__device__ __forceinline__ int lower_bound(const int* __restrict__ a, int v) {
    int lo = 0, hi = NE;
    while (lo < hi) {
        int mid = (lo + hi) >> 1;
        if (a[mid] < v) lo = mid + 1; else hi = mid;
    }
    return lo;
}

__device__ __forceinline__ float sigmoidf_(float v) {
    return 1.f / (1.f + __expf(-v));
}
__device__ __forceinline__ float tanhf_(float v) {
    v = fminf(v, 40.f);
    float t = __expf(2.f * v);
    return (t - 1.f) / (t + 1.f);
}

// ---------------------------------------------------------------------------
// Prepass: pathT[p][b*32+f] = fp16(path[b][p][f]). 8 floats/thread.
// lane -> (fh:2, b:3, p:...): reads 2x16B per lane, writes one 16B dwordx4;
// a wave's 32-lane half covers one p = 512B contiguous store.
// ---------------------------------------------------------------------------
__global__ __launch_bounds__(256) void transpose_kernel(
    const float* __restrict__ path, __half* __restrict__ pathT)
{
    const int id = blockIdx.x * 256 + threadIdx.x;
    const int fh = id & 3;          // 8-float chunk
    const int b  = (id >> 2) & 7;
    const int p  = id >> 5;
    const float* src = path + ((size_t)b * NP + p) * NF + fh * 8;
    floatx4 v0 = *(const floatx4*)(src);
    floatx4 v1 = *(const floatx4*)(src + 4);
    h8 o;
    o.a = __floats2half2_rn(v0[0], v0[1]);
    o.b = __floats2half2_rn(v0[2], v0[3]);
    o.c = __floats2half2_rn(v1[0], v1[1]);
    o.d = __floats2half2_rn(v1[2], v1[3]);
    *(h8*)(pathT + (size_t)p * (NB * NF) + b * NF + fh * 8) = o;
}

// ---------------------------------------------------------------------------
// Fused gather + GRU. USET=1: gather fp16 from pathT (512B/edge contiguous).
// USET=0: r9 fp32 gather from path (fallback when ws too small).
// ---------------------------------------------------------------------------
template <int USET>
__global__ __launch_bounds__(256) void fused_gru_kernel(
    const float*  __restrict__ path,         // [B,P,F] fp32
    const __half* __restrict__ pathT,        // [P,B,F] fp16 (d_ws)
    const float*  __restrict__ hbuf,         // [B,C,F] fp32
    const float*  __restrict__ W_ih,         // [96,32] fp32
    const float*  __restrict__ W_hh,         // [96,32] fp32
    const float*  __restrict__ b_ih,         // [96]
    const float*  __restrict__ b_hh,         // [96]
    const int*    __restrict__ edge_path,    // [E]
    const int*    __restrict__ edge_channel, // [E] sorted
    float*        __restrict__ out)          // [B,C,F] fp32
{
    const int t    = threadIdx.x;
    const int w    = t >> 6;      // wave 0..3
    const int lane = t & 63;
    const int cblk = blockIdx.x * 8;

    __shared__ int bounds[9];
    __shared__ __align__(16) short xs [64 * XROW];   // x rows, bf16, r = b*8+cl
    __shared__ __align__(16) short wsx[96 * XROW];   // W_ih bf16
    __shared__ __align__(16) short wsh[96 * XROW];   // W_hh bf16

    if (t < 9) bounds[t] = lower_bound(edge_channel, cblk + t);

    // Stage weights -> LDS bf16 once per block (24KB global, L2-hot).
    for (int idx = t; idx < 96 * NF; idx += 256) {
        int r = idx >> 5, c = idx & 31;
        wsx[r * XROW + c] = f2b(W_ih[idx]);
        wsh[r * XROW + c] = f2b(W_hh[idx]);
    }
    __syncthreads();   // bounds (and weights) visible

    // ---- Phase 1: ragged segment-sum gather. Wave w owns channels 2w, 2w+1
    // as ONE contiguous sorted edge range. lane = b*8 + fq.
    const int b  = lane >> 3;
    const int fq = lane & 7;
    const float*  prow  = path  + (size_t)b * (NP * NF) + fq * 4;
    const __half* prowT = pathT + b * NF + fq * 4;

    floatx4 acc0 = {0.f, 0.f, 0.f, 0.f};
    floatx4 acc1 = {0.f, 0.f, 0.f, 0.f};

    if (USET) {
        const int s0  = __builtin_amdgcn_readfirstlane(bounds[w * 2]);
        const int mid = __builtin_amdgcn_readfirstlane(bounds[w * 2 + 1]);
        const int e1  = __builtin_amdgcn_readfirstlane(bounds[w * 2 + 2]);

        // gulp: 16 gathers in flight (8KB/wave), fp16 pair pre-add.
        auto gulp16 = [&](int base, floatx4& acc) {
            int p[16];
            #pragma unroll
            for (int k = 0; k < 16; ++k) p[k] = edge_path[base + k];
            h4 g[16];
            #pragma unroll
            for (int k = 0; k < 16; ++k)
                g[k] = *(const h4*)(prowT + (size_t)p[k] * (NB * NF));
            floatx4 s = acc;
            #pragma unroll
            for (int k = 0; k < 8; ++k) {
                __half2 lo = __hadd2(g[2 * k].lo, g[2 * k + 1].lo);
                __half2 hi = __hadd2(g[2 * k].hi, g[2 * k + 1].hi);
                float2 fa = __half22float2(lo);
                float2 fb = __half22float2(hi);
                floatx4 v; v[0] = fa.x; v[1] = fa.y; v[2] = fb.x; v[3] = fb.y;
                s += v;
            }
            acc = s;
        };

        int i = s0;
        while (i + 16 <= e1) {
            if (i >= mid) {
                gulp16(i, acc1);
            } else if (i + 16 <= mid) {
                gulp16(i, acc0);
            } else {
                // the single chunk straddling the channel boundary
                #pragma unroll
                for (int k = 0; k < 16; ++k) {
                    floatx4 v = h4tof4(
                        *(const h4*)(prowT + (size_t)edge_path[i + k] * (NB * NF)));
                    if (i + k < mid) acc0 += v; else acc1 += v;   // uniform
                }
            }
            i += 16;
        }
        for (; i < e1; ++i) {
            floatx4 v = h4tof4(
                *(const h4*)(prowT + (size_t)edge_path[i] * (NB * NF)));
            if (i < mid) acc0 += v; else acc1 += v;               // uniform
        }
    } else {
        #pragma unroll
        for (int half = 0; half < 2; ++half) {
            const int s = __builtin_amdgcn_readfirstlane(bounds[w * 2 + half]);
            const int e = __builtin_amdgcn_readfirstlane(bounds[w * 2 + half + 1]);
            floatx4 acc = {0.f, 0.f, 0.f, 0.f};
            int i = s;
            for (; i + 8 <= e; i += 8) {
                int p0 = edge_path[i + 0], p1 = edge_path[i + 1];
                int p2 = edge_path[i + 2], p3 = edge_path[i + 3];
                int p4 = edge_path[i + 4], p5 = edge_path[i + 5];
                int p6 = edge_path[i + 6], p7 = edge_path[i + 7];
                floatx4 g0 = *(const floatx4*)(prow + (size_t)p0 * NF);
                floatx4 g1 = *(const floatx4*)(prow + (size_t)p1 * NF);
                floatx4 g2 = *(const floatx4*)(prow + (size_t)p2 * NF);
                floatx4 g3 = *(const floatx4*)(prow + (size_t)p3 * NF);
                floatx4 g4 = *(const floatx4*)(prow + (size_t)p4 * NF);
                floatx4 g5 = *(const floatx4*)(prow + (size_t)p5 * NF);
                floatx4 g6 = *(const floatx4*)(prow + (size_t)p6 * NF);
                floatx4 g7 = *(const floatx4*)(prow + (size_t)p7 * NF);
                acc += ((g0 + g1) + (g2 + g3)) + ((g4 + g5) + (g6 + g7));
            }
            for (; i < e; ++i)
                acc += *(const floatx4*)(prow + (size_t)edge_path[i] * NF);
            if (half == 0) acc0 = acc; else acc1 = acc;
        }
    }

    {
        short4v xb0, xb1;
        #pragma unroll
        for (int q = 0; q < 4; ++q) { xb0[q] = f2b(acc0[q]); xb1[q] = f2b(acc1[q]); }
        *(short4v*)(&xs[(b * 8 + w * 2)     * XROW + fq * 4]) = xb0;
        *(short4v*)(&xs[(b * 8 + w * 2 + 1) * XROW + fq * 4]) = xb1;
    }
    __syncthreads();

    // ---- Phase 2: fused GRU via mfma_f32_16x16x32_bf16. Wave w owns LDS
    // rows [16w, 16w+16) = 2 batches x 8 channels.
    const int quad = lane >> 4;
    const int n16  = lane & 15;
    const int k0   = quad * 8;

    const int rA = w * 16 + n16;
    short8 ax = *(const short8*)(&xs[rA * XROW + k0]);

    const int bA = rA >> 3;
    const int cA = cblk + (rA & 7);
    const float* hrow = hbuf + ((size_t)bA * NC + cA) * NF + k0;
    floatx4 h0 = *(const floatx4*)(hrow);
    floatx4 h1 = *(const floatx4*)(hrow + 4);
    short8 ah;
    #pragma unroll
    for (int q = 0; q < 4; ++q) { ah[q] = f2b(h0[q]); ah[4 + q] = f2b(h1[q]); }

    float bxv[6], bhv[6];
    #pragma unroll
    for (int tt = 0; tt < 6; ++tt) {
        bxv[tt] = b_ih[16 * tt + n16];
        bhv[tt] = b_hh[16 * tt + n16];
    }

    const floatx4 zero = {0.f, 0.f, 0.f, 0.f};
    // r,z gates: x- and h-MFMAs chain into ONE accumulator. n gate needs
    // xn and hn separate (r gates hn).
    floatx4 g[4];
    #pragma unroll
    for (int tt = 0; tt < 4; ++tt) {
        short8 bw = *(const short8*)(&wsx[(16 * tt + n16) * XROW + k0]);
        floatx4 a = __builtin_amdgcn_mfma_f32_16x16x32_bf16(ax, bw, zero, 0, 0, 0);
        bw = *(const short8*)(&wsh[(16 * tt + n16) * XROW + k0]);
        g[tt] = __builtin_amdgcn_mfma_f32_16x16x32_bf16(ah, bw, a, 0, 0, 0);
    }
    floatx4 nx[2], nh[2];
    #pragma unroll
    for (int u = 0; u < 2; ++u) {
        const int tt = 4 + u;
        short8 bw = *(const short8*)(&wsx[(16 * tt + n16) * XROW + k0]);
        nx[u] = __builtin_amdgcn_mfma_f32_16x16x32_bf16(ax, bw, zero, 0, 0, 0);
        bw = *(const short8*)(&wsh[(16 * tt + n16) * XROW + k0]);
        nh[u] = __builtin_amdgcn_mfma_f32_16x16x32_bf16(ah, bw, zero, 0, 0, 0);
    }

    // Epilogue in C-layout (col = lane&15, row = quad*4+i), fp32 h blend.
    #pragma unroll
    for (int i = 0; i < 4; ++i) {
        const int r  = w * 16 + quad * 4 + i;
        const int b2 = r >> 3;
        const size_t m = (size_t)b2 * NC + (cblk + (r & 7));
        float r0 = sigmoidf_(g[0][i] + bxv[0] + bhv[0]);
        float r1 = sigmoidf_(g[1][i] + bxv[1] + bhv[1]);
        float z0 = sigmoidf_(g[2][i] + bxv[2] + bhv[2]);
        float z1 = sigmoidf_(g[3][i] + bxv[3] + bhv[3]);
        float n0 = tanhf_(nx[0][i] + bxv[4] + r0 * (nh[0][i] + bhv[4]));
        float n1 = tanhf_(nx[1][i] + bxv[5] + r1 * (nh[1][i] + bhv[5]));
        float hv0 = hbuf[m * NF + n16];
        float hv1 = hbuf[m * NF + 16 + n16];
        out[m * NF + n16]      = (1.f - z0) * n0 + z0 * hv0;
        out[m * NF + 16 + n16] = (1.f - z1) * n1 + z1 * hv1;
    }
}

extern "C" void kernel_launch(void* const* d_in, const int* in_sizes, int n_in,
                              void* d_out, int out_size, void* d_ws, size_t ws_size,
                              hipStream_t stream) {
    const float* path = (const float*)d_in[0];  // [8,65536,32] fp32
    const float* chan = (const float*)d_in[1];  // [8,32768,32] fp32
    const float* W_ih = (const float*)d_in[2];  // [96,32]
    const float* W_hh = (const float*)d_in[3];  // [96,32]
    const float* b_ih = (const float*)d_in[4];  // [96]
    const float* b_hh = (const float*)d_in[5];  // [96]
    const int* edge_path    = (const int*)d_in[6];
    const int* edge_channel = (const int*)d_in[7];
    float* out = (float*)d_out;                 // [8,32768,32] fp32

    const size_t needT = (size_t)NP * NB * NF * sizeof(__half);  // 32MB
    if (ws_size >= needT) {
        __half* pathT = (__half*)d_ws;
        transpose_kernel<<<dim3((NP * NB * 4) / 256), dim3(256), 0, stream>>>(
            path, pathT);
        fused_gru_kernel<1><<<dim3(NC / 8), dim3(256), 0, stream>>>(
            path, pathT, chan, W_ih, W_hh, b_ih, b_hh, edge_path, edge_channel, out);
    } else {
        fused_gru_kernel<0><<<dim3(NC / 8), dim3(256), 0, stream>>>(
            path, (const __half*)nullptr, chan, W_ih, W_hh, b_ih, b_hh,
            edge_path, edge_channel, out);
    }
}